// Round 2
// baseline (7079.256 us; speedup 1.0000x reference)
//
#include <hip/hip_runtime.h>

// WindowAttention — Round 2: register-blocked attention core.
// QKV/proj GEMMs stay on split-bf16 MFMA (Round 1). Attention core redesigned:
//   32 groups x 8 lanes; group owns 4 q-rows of one head (26 tasks/pass).
//   q,k staged as f16 in LDS (stride 56 halves, conflict-free), dot via
//   v_dot2_f32_f16 (fp32 acc). Softmax = width-8 shfl_xor reduce (all lanes).
//   PV d-sliced (lane owns 4 dims), P broadcast by __shfl width 8.
//   2 barriers/pass (was 7). LDS 36 KB (was 52) -> ~4 blocks/CU.
// biasT = rpb[rel] pre-gathered into d_ws (kills dependent 2-deep gather).

#define NWIN 4096
#define NW_MASK 1024
#define NH 12
#define DIM 384
#define HD 32
#define NT 49
#define SCALEF 0.17677669529663687f

typedef __attribute__((ext_vector_type(4))) float f32x4;
typedef __attribute__((ext_vector_type(8))) __bf16 bf16x8;
typedef __attribute__((ext_vector_type(4))) unsigned int u32x4;
typedef __attribute__((ext_vector_type(2))) _Float16 h2;

#define MFMA16(A, B, C) __builtin_amdgcn_mfma_f32_16x16x32_bf16( \
    __builtin_bit_cast(bf16x8, A), __builtin_bit_cast(bf16x8, B), (C), 0, 0, 0)

#if defined(__has_builtin)
#if __has_builtin(__builtin_amdgcn_fdot2)
#define HAS_FDOT2 1
#endif
#endif

__device__ __forceinline__ float fdot2u(unsigned a, unsigned b, float c) {
#ifdef HAS_FDOT2
    return __builtin_amdgcn_fdot2(__builtin_bit_cast(h2, a),
                                  __builtin_bit_cast(h2, b), c, false);
#else
    h2 av = __builtin_bit_cast(h2, a), bv = __builtin_bit_cast(h2, b);
    return c + (float)av.x * (float)bv.x + (float)av.y * (float)bv.y;
#endif
}

// split fp32 pair -> packed bf16 hi + packed bf16 lo (truncation split)
__device__ __forceinline__ void split2(float x0, float x1, unsigned& h, unsigned& l) {
    unsigned b0 = __float_as_uint(x0), b1 = __float_as_uint(x1);
    unsigned m0 = b0 & 0xffff0000u, m1 = b1 & 0xffff0000u;
    h = m1 | (m0 >> 16);
    float r0 = x0 - __uint_as_float(m0);
    float r1 = x1 - __uint_as_float(m1);
    l = (__float_as_uint(r1) & 0xffff0000u) | (__float_as_uint(r0) >> 16);
}

__device__ __forceinline__ void cvt8(const float4& a, const float4& c,
                                     u32x4& hi, u32x4& lo) {
    unsigned h0, l0, h1, l1, h2_, l2, h3, l3;
    split2(a.x, a.y, h0, l0);
    split2(a.z, a.w, h1, l1);
    split2(c.x, c.y, h2_, l2);
    split2(c.z, c.w, h3, l3);
    hi = u32x4{h0, h1, h2_, h3};
    lo = u32x4{l0, l1, l2, l3};
}

// ---- weight fragment builder + biasT pre-gather ----
__global__ __launch_bounds__(256)
void conv_w(const float* __restrict__ qkv_w, const float* __restrict__ proj_w,
            const float* __restrict__ rpb, const int* __restrict__ rel,
            u32x4* __restrict__ wf, float* __restrict__ biasT)
{
    if (blockIdx.x < 288) {
        int tg = blockIdx.x * 256 + threadIdx.x;
        int fid = tg >> 6, lane = tg & 63;
        int kt = fid / 96, ntc = fid - kt * 96;
        const float* src; int ncols, n; u32x4* dst;
        if (ntc < 72) {
            src = qkv_w; ncols = 3 * DIM; n = ntc * 16 + (lane & 15);
            dst = wf + (size_t)((kt * 72 + ntc) * 128);
        } else {
            int nt2 = ntc - 72;
            src = proj_w; ncols = DIM; n = nt2 * 16 + (lane & 15);
            dst = wf + (size_t)(12 * 72 * 128) + (size_t)((kt * 24 + nt2) * 128);
        }
        int k0 = kt * 32 + ((lane >> 4) << 3);
        float e[8];
        #pragma unroll
        for (int j = 0; j < 8; ++j) e[j] = src[(size_t)(k0 + j) * ncols + n];
        float4 a = make_float4(e[0], e[1], e[2], e[3]);
        float4 c = make_float4(e[4], e[5], e[6], e[7]);
        u32x4 hi, lo; cvt8(a, c, hi, lo);
        dst[lane] = hi; dst[64 + lane] = lo;
    } else {
        int tid = (blockIdx.x - 288) * 256 + threadIdx.x;
        if (tid < NH * NT * NT) {
            int h = tid / (NT * NT);
            int idx = tid - h * (NT * NT);
            biasT[tid] = rpb[rel[idx] * NH + h];
        }
    }
}

// ---- fused window attention ----
__global__ __launch_bounds__(256, 3)
void attn_mfma(const float* __restrict__ x,
               const float* __restrict__ mask,
               const float* __restrict__ qkv_b,
               const float* __restrict__ biasT,   // (12, 49*49)
               const u32x4* __restrict__ wf,
               float* __restrict__ y)
{
    __shared__ __align__(16) _Float16 qs16[2][NT * 56];  // 10976 B (q pre-scaled)
    __shared__ __align__(16) _Float16 ks16[2][NT * 56];  // 10976 B
    __shared__ __align__(16) float    vs[2][NT * 36];    // 14112 B  -> 36064 total

    const int b = blockIdx.x;
    const int t = threadIdx.x;
    const int lane = t & 63;
    const int wid = t >> 6;
    const int h_l = wid >> 1;          // QKV: head slot in pass
    const int mhalf = wid & 1;         // QKV: row half
    const int lrow = lane & 15;
    const int lk8 = (lane >> 4) << 3;
    const int lr4 = (lane >> 4) << 2;
    const float* xb = x + (size_t)b * (NT * DIM);
    const float* mrow = mask + (size_t)(b & (NW_MASK - 1)) * (NT * NT);
    const u32x4* wfl = wf + lane;

    // attention-core task decode: 32 groups x 8 lanes; 26 tasks
    const int g  = t >> 3;
    const int j8 = t & 7;
    const int hh = (g < 13) ? 0 : 1;
    const int rq = g - hh * 13;        // 0..12 row-quad (valid when g<26)
    const int n0 = rq * 4;
    const int nrows = (rq == 12) ? 1 : 4;
    const bool act = g < 26;

    for (int pass = 0; pass < 6; ++pass) {
        const int h = pass * 2 + h_l;
        int gnt[6];
        #pragma unroll
        for (int ln = 0; ln < 6; ++ln)
            gnt[ln] = (ln >> 1) * 24 + 2 * h + (ln & 1);

        f32x4 acc[2][6];
        #pragma unroll
        for (int mt = 0; mt < 2; ++mt)
            #pragma unroll
            for (int ln = 0; ln < 6; ++ln)
                acc[mt][ln] = f32x4{0.f, 0.f, 0.f, 0.f};

        for (int kt = 0; kt < 12; ++kt) {
            u32x4 ah[2], al[2];
            #pragma unroll
            for (int mt = 0; mt < 2; ++mt) {
                int row = mhalf * 32 + mt * 16 + lrow;
                float4 a = make_float4(0.f, 0.f, 0.f, 0.f);
                float4 c = make_float4(0.f, 0.f, 0.f, 0.f);
                if (row < NT) {
                    const float4* px = (const float4*)(xb + row * DIM + kt * 32 + lk8);
                    a = px[0]; c = px[1];
                }
                cvt8(a, c, ah[mt], al[mt]);
            }
            #pragma unroll
            for (int ln = 0; ln < 6; ++ln) {
                const u32x4* bp = wfl + (kt * 72 + gnt[ln]) * 128;
                u32x4 bh = bp[0], bl = bp[64];
                #pragma unroll
                for (int mt = 0; mt < 2; ++mt) {
                    acc[mt][ln] = MFMA16(al[mt], bh, acc[mt][ln]);
                    acc[mt][ln] = MFMA16(ah[mt], bl, acc[mt][ln]);
                    acc[mt][ln] = MFMA16(ah[mt], bh, acc[mt][ln]);
                }
            }
        }

        __syncthreads();   // prev pass attention done reading LDS

        // C scatter: q (scaled, f16), k (f16), v (f32). C map: col=lane&15,
        // row=(lane>>4)*4+r
        #pragma unroll
        for (int ln = 0; ln < 6; ++ln) {
            int cc = ln * 16 + lrow;
            int p = cc >> 5, d = cc & 31;
            float bias = qkv_b[p * DIM + h * HD + d];
            #pragma unroll
            for (int mt = 0; mt < 2; ++mt) {
                #pragma unroll
                for (int r = 0; r < 4; ++r) {
                    int row = mhalf * 32 + mt * 16 + lr4 + r;
                    if (row < NT) {
                        float v = acc[mt][ln][r] + bias;
                        if (p == 0)      qs16[h_l][row * 56 + d] = (_Float16)(v * SCALEF);
                        else if (p == 1) ks16[h_l][row * 56 + d] = (_Float16)v;
                        else             vs[h_l][row * 36 + d] = v;
                    }
                }
            }
        }
        __syncthreads();

        if (act) {
            const int hg = pass * 2 + hh;
            const float* bT = biasT + hg * (NT * NT);

            // hold the group's 4 q-rows as packed f16 pairs (64 VGPR)
            unsigned qreg[4][16];
            #pragma unroll
            for (int r = 0; r < 4; ++r) {
                if (r < nrows) {
                    const u32x4* qp = (const u32x4*)&qs16[hh][(n0 + r) * 56];
                    #pragma unroll
                    for (int w = 0; w < 4; ++w) {
                        u32x4 qv = qp[w];
                        qreg[r][w * 4 + 0] = qv[0];
                        qreg[r][w * 4 + 1] = qv[1];
                        qreg[r][w * 4 + 2] = qv[2];
                        qreg[r][w * 4 + 3] = qv[3];
                    }
                }
            }

            // logits: lane j8 handles m = j8 + 8i
            float P[4][7];
            #pragma unroll
            for (int i = 0; i < 7; ++i) {
                int m = j8 + 8 * i;
                bool vm = m < NT;
                u32x4 kw0{}, kw1{}, kw2{}, kw3{};
                if (vm) {
                    const u32x4* kp = (const u32x4*)&ks16[hh][m * 56];
                    kw0 = kp[0]; kw1 = kp[1]; kw2 = kp[2]; kw3 = kp[3];
                }
                #pragma unroll
                for (int r = 0; r < 4; ++r) {
                    if (r < nrows) {
                        float lv = -1e30f;
                        if (vm) {
                            float dsum = 0.f;
                            #pragma unroll
                            for (int c = 0; c < 4; ++c) dsum = fdot2u(qreg[r][c], kw0[c], dsum);
                            #pragma unroll
                            for (int c = 0; c < 4; ++c) dsum = fdot2u(qreg[r][4 + c], kw1[c], dsum);
                            #pragma unroll
                            for (int c = 0; c < 4; ++c) dsum = fdot2u(qreg[r][8 + c], kw2[c], dsum);
                            #pragma unroll
                            for (int c = 0; c < 4; ++c) dsum = fdot2u(qreg[r][12 + c], kw3[c], dsum);
                            int idx = (n0 + r) * NT + m;
                            lv = dsum + bT[idx] + mrow[idx];
                        }
                        P[r][i] = lv;
                    }
                }
            }

            // softmax: width-8 butterfly (group-uniform branches -> shfl safe)
            #pragma unroll
            for (int r = 0; r < 4; ++r) {
                if (r < nrows) {
                    float mx = P[r][0];
                    #pragma unroll
                    for (int i = 1; i < 7; ++i) mx = fmaxf(mx, P[r][i]);
                    mx = fmaxf(mx, __shfl_xor(mx, 1, 8));
                    mx = fmaxf(mx, __shfl_xor(mx, 2, 8));
                    mx = fmaxf(mx, __shfl_xor(mx, 4, 8));
                    float sm = 0.f;
                    #pragma unroll
                    for (int i = 0; i < 7; ++i) {
                        float e = __expf(P[r][i] - mx);
                        P[r][i] = e; sm += e;
                    }
                    sm += __shfl_xor(sm, 1, 8);
                    sm += __shfl_xor(sm, 2, 8);
                    sm += __shfl_xor(sm, 4, 8);
                    float inv = 1.f / sm;
                    #pragma unroll
                    for (int i = 0; i < 7; ++i) P[r][i] *= inv;
                }
            }

            // PV: lane owns d = j8*4..+3; P broadcast by width-8 shfl
            f32x4 oacc[4];
            #pragma unroll
            for (int r = 0; r < 4; ++r) oacc[r] = f32x4{0.f, 0.f, 0.f, 0.f};
            #pragma unroll
            for (int i8 = 0; i8 < 7; ++i8) {
                #pragma unroll
                for (int jj = 0; jj < 8; ++jj) {
                    const int mm = i8 * 8 + jj;
                    if (mm < NT) {
                        f32x4 v4 = *(const f32x4*)&vs[hh][mm * 36 + j8 * 4];
                        #pragma unroll
                        for (int r = 0; r < 4; ++r) {
                            if (r < nrows) {
                                float p = __shfl(P[r][i8], jj, 8);
                                oacc[r] += v4 * p;
                            }
                        }
                    }
                }
            }
            #pragma unroll
            for (int r = 0; r < 4; ++r) {
                if (r < nrows) {
                    *(f32x4*)&y[((size_t)b * NT + (n0 + r)) * DIM + hg * HD + j8 * 4] = oacc[r];
                }
            }
        }
        // next pass's first __syncthreads() protects LDS
    }
}

// ---- in-place output projection via split-MFMA ----
__global__ __launch_bounds__(256, 3)
void proj_mfma(const u32x4* __restrict__ pwf,
               const float* __restrict__ proj_b,
               float* __restrict__ y)
{
    const int t = threadIdx.x;
    const int lane = t & 63;
    const int wid = t >> 6;
    const int mhalf = wid >> 1, nhalf = wid & 1;
    const int lrow = lane & 15;
    const int lk8 = (lane >> 4) << 3;
    const int lr4 = (lane >> 4) << 2;
    float* yb = y + (size_t)blockIdx.x * (64 * DIM);
    const u32x4* pwl = pwf + lane;

    f32x4 acc[2][12];
    #pragma unroll
    for (int mt = 0; mt < 2; ++mt)
        #pragma unroll
        for (int ln = 0; ln < 12; ++ln)
            acc[mt][ln] = f32x4{0.f, 0.f, 0.f, 0.f};

    for (int kt = 0; kt < 12; ++kt) {
        u32x4 ah[2], al[2];
        #pragma unroll
        for (int mt = 0; mt < 2; ++mt) {
            int row = mhalf * 32 + mt * 16 + lrow;
            const float4* px = (const float4*)(yb + row * DIM + kt * 32 + lk8);
            float4 a = px[0], c = px[1];
            cvt8(a, c, ah[mt], al[mt]);
        }
        #pragma unroll
        for (int ln = 0; ln < 12; ++ln) {
            const u32x4* bp = pwl + (kt * 24 + nhalf * 12 + ln) * 128;
            u32x4 bh = bp[0], bl = bp[64];
            #pragma unroll
            for (int mt = 0; mt < 2; ++mt) {
                acc[mt][ln] = MFMA16(al[mt], bh, acc[mt][ln]);
                acc[mt][ln] = MFMA16(ah[mt], bl, acc[mt][ln]);
                acc[mt][ln] = MFMA16(ah[mt], bh, acc[mt][ln]);
            }
        }
    }
    __syncthreads();   // partner waves still read these rows until here
    #pragma unroll
    for (int ln = 0; ln < 12; ++ln) {
        int col = (nhalf * 12 + ln) * 16 + lrow;
        float bias = proj_b[col];
        #pragma unroll
        for (int mt = 0; mt < 2; ++mt)
            #pragma unroll
            for (int r = 0; r < 4; ++r) {
                int row = mhalf * 32 + mt * 16 + lr4 + r;
                yb[row * DIM + col] = acc[mt][ln][r] + bias;
            }
    }
}

// ================== fallback path (fp32, no-ws) ==================
#define HD_P 33
#define CHUNK 128
#define THREADS_A 384

__global__ __launch_bounds__(THREADS_A)
void win_attn_kernel(const float* __restrict__ x,
                     const float* __restrict__ mask,
                     const float* __restrict__ qkv_w,
                     const float* __restrict__ qkv_b,
                     const float* __restrict__ rpb,
                     const int*   __restrict__ rel,
                     float* __restrict__ y)
{
    __shared__ float xs[NT * CHUNK];
    __shared__ float qs[NT * HD_P];
    __shared__ float ks_[NT * HD_P];
    __shared__ float vsf[NT * HD_P];
    __shared__ float lg[NT * NT];

    const int b = blockIdx.x;
    const int t = threadIdx.x;
    const float* xb = x + (size_t)b * (NT * DIM);
    const float* mrow = mask + (size_t)(b & (NW_MASK - 1)) * (NT * NT);

    const int tx = t % 96;
    const int ty = t / 96;
    const int p  = tx / 32;
    const int d  = tx % 32;

    for (int h = 0; h < NH; ++h) {
        float acc[13];
        #pragma unroll
        for (int i = 0; i < 13; ++i) acc[i] = 0.f;
        const int wcol = p * DIM + h * HD + d;

        for (int c = 0; c < 3; ++c) {
            __syncthreads();
            for (int i = t; i < NT * (CHUNK / 4); i += THREADS_A) {
                int r = i >> 5;
                int j = i & 31;
                ((float4*)xs)[i] = ((const float4*)xb)[r * 96 + c * 32 + j];
            }
            __syncthreads();
            const float4* xs4 = (const float4*)xs;
            const float* wb = qkv_w + (size_t)(c * CHUNK) * (3 * DIM) + wcol;
            for (int kk4 = 0; kk4 < CHUNK / 4; ++kk4) {
                float w0 = wb[(size_t)(kk4 * 4 + 0) * (3 * DIM)];
                float w1 = wb[(size_t)(kk4 * 4 + 1) * (3 * DIM)];
                float w2 = wb[(size_t)(kk4 * 4 + 2) * (3 * DIM)];
                float w3 = wb[(size_t)(kk4 * 4 + 3) * (3 * DIM)];
                #pragma unroll
                for (int i = 0; i < 13; ++i) {
                    int r = ty + 4 * i;
                    if (r < NT) {
                        float4 xv = xs4[r * 32 + kk4];
                        acc[i] += xv.x * w0;
                        acc[i] += xv.y * w1;
                        acc[i] += xv.z * w2;
                        acc[i] += xv.w * w3;
                    }
                }
            }
        }
        float bv = qkv_b[wcol];
        float* dst = (p == 0) ? qs : (p == 1) ? ks_ : vsf;
        #pragma unroll
        for (int i = 0; i < 13; ++i) {
            int r = ty + 4 * i;
            if (r < NT) dst[r * HD_P + d] = acc[i] + bv;
        }
        __syncthreads();

        for (int idx = t; idx < NT * NT; idx += THREADS_A) {
            int n = idx / NT, m = idx % NT;
            float s = 0.f;
            #pragma unroll
            for (int kk = 0; kk < HD; ++kk)
                s += qs[n * HD_P + kk] * ks_[m * HD_P + kk];
            s = s * SCALEF + rpb[rel[idx] * NH + h] + mrow[idx];
            lg[idx] = s;
        }
        __syncthreads();

        if (t < NT) {
            float mx = -1e30f;
            for (int m = 0; m < NT; ++m) mx = fmaxf(mx, lg[t * NT + m]);
            float sum = 0.f;
            for (int m = 0; m < NT; ++m) {
                float e = __expf(lg[t * NT + m] - mx);
                lg[t * NT + m] = e;
                sum += e;
            }
            float inv = 1.f / sum;
            for (int m = 0; m < NT; ++m) lg[t * NT + m] *= inv;
        }
        __syncthreads();

        for (int idx = t; idx < NT * HD; idx += THREADS_A) {
            int n = idx >> 5, dd = idx & 31;
            float s = 0.f;
            #pragma unroll
            for (int m = 0; m < NT; ++m)
                s += lg[n * NT + m] * vsf[m * HD_P + dd];
            y[(size_t)b * (NT * DIM) + n * DIM + h * HD + dd] = s;
        }
    }
}

#define RPB 16
__global__ __launch_bounds__(384)
void proj_kernel(const float* __restrict__ proj_w,
                 const float* __restrict__ proj_b,
                 float* __restrict__ y)
{
    __shared__ float ys[RPB * DIM];
    const int t = threadIdx.x;
    float* base = y + (size_t)blockIdx.x * (RPB * DIM);
    for (int i = t; i < RPB * DIM / 4; i += 384)
        ((float4*)ys)[i] = ((const float4*)base)[i];
    __syncthreads();

    float acc[RPB];
    #pragma unroll
    for (int i = 0; i < RPB; ++i) acc[i] = 0.f;
    const float* wp = proj_w + t;
    const float4* ys4 = (const float4*)ys;
    for (int kk4 = 0; kk4 < DIM / 4; ++kk4) {
        float w0 = wp[(kk4 * 4 + 0) * DIM];
        float w1 = wp[(kk4 * 4 + 1) * DIM];
        float w2 = wp[(kk4 * 4 + 2) * DIM];
        float w3 = wp[(kk4 * 4 + 3) * DIM];
        #pragma unroll
        for (int i = 0; i < RPB; ++i) {
            float4 xv = ys4[i * 96 + kk4];
            acc[i] += xv.x * w0 + xv.y * w1 + xv.z * w2 + xv.w * w3;
        }
    }
    float bv = proj_b[t];
    #pragma unroll
    for (int i = 0; i < RPB; ++i)
        base[i * DIM + t] = acc[i] + bv;
}

// ================== launch ==================
extern "C" void kernel_launch(void* const* d_in, const int* in_sizes, int n_in,
                              void* d_out, int out_size, void* d_ws, size_t ws_size,
                              hipStream_t stream) {
    const float* x      = (const float*)d_in[0];
    const float* mask   = (const float*)d_in[1];
    const float* qkv_w  = (const float*)d_in[2];
    const float* qkv_b  = (const float*)d_in[3];
    const float* proj_w = (const float*)d_in[4];
    const float* proj_b = (const float*)d_in[5];
    const float* rpb    = (const float*)d_in[6];
    const int*   rel    = (const int*)d_in[7];
    float* out = (float*)d_out;

    const size_t WS_FRAG = (size_t)(12 * 96 * 128) * 16;       // 2,359,296 B
    const size_t WS_NEED = WS_FRAG + (size_t)NH * NT * NT * 4; // + 115,248 B
    if (d_ws != nullptr && ws_size >= WS_NEED) {
        u32x4* wf = (u32x4*)d_ws;
        float* biasT = (float*)((char*)d_ws + WS_FRAG);
        conv_w<<<401, 256, 0, stream>>>(qkv_w, proj_w, rpb, rel, wf, biasT);
        attn_mfma<<<NWIN, 256, 0, stream>>>(x, mask, qkv_b, biasT, wf, out);
        proj_mfma<<<(NWIN * NT) / 64, 256, 0, stream>>>(wf + (size_t)(12 * 72 * 128), proj_b, out);
    } else {
        win_attn_kernel<<<NWIN, THREADS_A, 0, stream>>>(x, mask, qkv_w, qkv_b, rpb, rel, out);
        proj_kernel<<<(NWIN * NT) / RPB, 384, 0, stream>>>(proj_w, proj_b, out);
    }
}

// Round 3
// 3380.808 us; speedup vs baseline: 2.0940x; 2.0940x over previous
//
#include <hip/hip_runtime.h>

// WindowAttention — Round 3: fix R2's scratch-spill catastrophe.
// R2 evidence: VGPR=84 (forced by __launch_bounds__(256,3)), FETCH/WRITE +5.5GB
// symmetric (scratch thrash), VALUBusy 7%. Fix: (a) drop min-waves bound,
// (b) halve per-thread state: 4 q-rows processed as 2 sequential 2-row chunks
// (qreg[2][16]+P[2][7]+oacc[2] ~= 54 regs vs 108). All indices compile-time.
// QKV/proj GEMMs unchanged (split-bf16 MFMA, R1-verified).

#define NWIN 4096
#define NW_MASK 1024
#define NH 12
#define DIM 384
#define HD 32
#define NT 49
#define SCALEF 0.17677669529663687f

typedef __attribute__((ext_vector_type(4))) float f32x4;
typedef __attribute__((ext_vector_type(8))) __bf16 bf16x8;
typedef __attribute__((ext_vector_type(4))) unsigned int u32x4;
typedef __attribute__((ext_vector_type(2))) _Float16 h2;

#define MFMA16(A, B, C) __builtin_amdgcn_mfma_f32_16x16x32_bf16( \
    __builtin_bit_cast(bf16x8, A), __builtin_bit_cast(bf16x8, B), (C), 0, 0, 0)

#if defined(__has_builtin)
#if __has_builtin(__builtin_amdgcn_fdot2)
#define HAS_FDOT2 1
#endif
#endif

__device__ __forceinline__ float fdot2u(unsigned a, unsigned b, float c) {
#ifdef HAS_FDOT2
    return __builtin_amdgcn_fdot2(__builtin_bit_cast(h2, a),
                                  __builtin_bit_cast(h2, b), c, false);
#else
    h2 av = __builtin_bit_cast(h2, a), bv = __builtin_bit_cast(h2, b);
    return c + (float)av.x * (float)bv.x + (float)av.y * (float)bv.y;
#endif
}

// split fp32 pair -> packed bf16 hi + packed bf16 lo (truncation split)
__device__ __forceinline__ void split2(float x0, float x1, unsigned& h, unsigned& l) {
    unsigned b0 = __float_as_uint(x0), b1 = __float_as_uint(x1);
    unsigned m0 = b0 & 0xffff0000u, m1 = b1 & 0xffff0000u;
    h = m1 | (m0 >> 16);
    float r0 = x0 - __uint_as_float(m0);
    float r1 = x1 - __uint_as_float(m1);
    l = (__float_as_uint(r1) & 0xffff0000u) | (__float_as_uint(r0) >> 16);
}

__device__ __forceinline__ void cvt8(const float4& a, const float4& c,
                                     u32x4& hi, u32x4& lo) {
    unsigned h0, l0, h1, l1, h2_, l2, h3, l3;
    split2(a.x, a.y, h0, l0);
    split2(a.z, a.w, h1, l1);
    split2(c.x, c.y, h2_, l2);
    split2(c.z, c.w, h3, l3);
    hi = u32x4{h0, h1, h2_, h3};
    lo = u32x4{l0, l1, l2, l3};
}

// ---- weight fragment builder + biasT pre-gather ----
__global__ __launch_bounds__(256)
void conv_w(const float* __restrict__ qkv_w, const float* __restrict__ proj_w,
            const float* __restrict__ rpb, const int* __restrict__ rel,
            u32x4* __restrict__ wf, float* __restrict__ biasT)
{
    if (blockIdx.x < 288) {
        int tg = blockIdx.x * 256 + threadIdx.x;
        int fid = tg >> 6, lane = tg & 63;
        int kt = fid / 96, ntc = fid - kt * 96;
        const float* src; int ncols, n; u32x4* dst;
        if (ntc < 72) {
            src = qkv_w; ncols = 3 * DIM; n = ntc * 16 + (lane & 15);
            dst = wf + (size_t)((kt * 72 + ntc) * 128);
        } else {
            int nt2 = ntc - 72;
            src = proj_w; ncols = DIM; n = nt2 * 16 + (lane & 15);
            dst = wf + (size_t)(12 * 72 * 128) + (size_t)((kt * 24 + nt2) * 128);
        }
        int k0 = kt * 32 + ((lane >> 4) << 3);
        float e[8];
        #pragma unroll
        for (int j = 0; j < 8; ++j) e[j] = src[(size_t)(k0 + j) * ncols + n];
        float4 a = make_float4(e[0], e[1], e[2], e[3]);
        float4 c = make_float4(e[4], e[5], e[6], e[7]);
        u32x4 hi, lo; cvt8(a, c, hi, lo);
        dst[lane] = hi; dst[64 + lane] = lo;
    } else {
        int tid = (blockIdx.x - 288) * 256 + threadIdx.x;
        if (tid < NH * NT * NT) {
            int h = tid / (NT * NT);
            int idx = tid - h * (NT * NT);
            biasT[tid] = rpb[rel[idx] * NH + h];
        }
    }
}

// ---- fused window attention ----
__global__ __launch_bounds__(256)
void attn_mfma(const float* __restrict__ x,
               const float* __restrict__ mask,
               const float* __restrict__ qkv_b,
               const float* __restrict__ biasT,   // (12, 49*49)
               const u32x4* __restrict__ wf,
               float* __restrict__ y)
{
    __shared__ __align__(16) _Float16 qs16[2][NT * 56];  // 10976 B (q pre-scaled)
    __shared__ __align__(16) _Float16 ks16[2][NT * 56];  // 10976 B
    __shared__ __align__(16) float    vs[2][NT * 36];    // 14112 B  -> 36064 total

    const int b = blockIdx.x;
    const int t = threadIdx.x;
    const int lane = t & 63;
    const int wid = t >> 6;
    const int h_l = wid >> 1;          // QKV: head slot in pass
    const int mhalf = wid & 1;         // QKV: row half
    const int lrow = lane & 15;
    const int lk8 = (lane >> 4) << 3;
    const int lr4 = (lane >> 4) << 2;
    const float* xb = x + (size_t)b * (NT * DIM);
    const float* mrow = mask + (size_t)(b & (NW_MASK - 1)) * (NT * NT);
    const u32x4* wfl = wf + lane;

    // attention-core task decode: 32 groups x 8 lanes; 26 active tasks
    const int g  = t >> 3;
    const int j8 = t & 7;
    const int hh = (g < 13) ? 0 : 1;
    const int rq = g - hh * 13;        // 0..12 row-quad (valid when g<26)
    const int n0 = rq * 4;
    const bool act = g < 26;

    for (int pass = 0; pass < 6; ++pass) {
        const int h = pass * 2 + h_l;
        int gnt[6];
        #pragma unroll
        for (int ln = 0; ln < 6; ++ln)
            gnt[ln] = (ln >> 1) * 24 + 2 * h + (ln & 1);

        f32x4 acc[2][6];
        #pragma unroll
        for (int mt = 0; mt < 2; ++mt)
            #pragma unroll
            for (int ln = 0; ln < 6; ++ln)
                acc[mt][ln] = f32x4{0.f, 0.f, 0.f, 0.f};

        for (int kt = 0; kt < 12; ++kt) {
            u32x4 ah[2], al[2];
            #pragma unroll
            for (int mt = 0; mt < 2; ++mt) {
                int row = mhalf * 32 + mt * 16 + lrow;
                float4 a = make_float4(0.f, 0.f, 0.f, 0.f);
                float4 c = make_float4(0.f, 0.f, 0.f, 0.f);
                if (row < NT) {
                    const float4* px = (const float4*)(xb + row * DIM + kt * 32 + lk8);
                    a = px[0]; c = px[1];
                }
                cvt8(a, c, ah[mt], al[mt]);
            }
            #pragma unroll
            for (int ln = 0; ln < 6; ++ln) {
                const u32x4* bp = wfl + (kt * 72 + gnt[ln]) * 128;
                u32x4 bh = bp[0], bl = bp[64];
                #pragma unroll
                for (int mt = 0; mt < 2; ++mt) {
                    acc[mt][ln] = MFMA16(al[mt], bh, acc[mt][ln]);
                    acc[mt][ln] = MFMA16(ah[mt], bl, acc[mt][ln]);
                    acc[mt][ln] = MFMA16(ah[mt], bh, acc[mt][ln]);
                }
            }
        }

        __syncthreads();   // prev pass attention done reading LDS

        // C scatter: q (scaled, f16), k (f16), v (f32). C map: col=lane&15,
        // row=(lane>>4)*4+r
        #pragma unroll
        for (int ln = 0; ln < 6; ++ln) {
            int cc = ln * 16 + lrow;
            int p = cc >> 5, d = cc & 31;
            float bias = qkv_b[p * DIM + h * HD + d];
            #pragma unroll
            for (int mt = 0; mt < 2; ++mt) {
                #pragma unroll
                for (int r = 0; r < 4; ++r) {
                    int row = mhalf * 32 + mt * 16 + lr4 + r;
                    if (row < NT) {
                        float v = acc[mt][ln][r] + bias;
                        if (p == 0)      qs16[h_l][row * 56 + d] = (_Float16)(v * SCALEF);
                        else if (p == 1) ks16[h_l][row * 56 + d] = (_Float16)v;
                        else             vs[h_l][row * 36 + d] = v;
                    }
                }
            }
        }
        __syncthreads();

        if (act) {
            const int hg = pass * 2 + hh;
            const float* bT = biasT + hg * (NT * NT);

            // 2-row chunks: half=0 -> rows n0,n0+1 ; half=1 -> rows n0+2,n0+3
            for (int half = 0; half < 2; ++half) {
                const int r0 = n0 + 2 * half;
                if (r0 >= NT) break;                 // group-uniform
                const int nr = (NT - r0 >= 2) ? 2 : 1;

                // q rows in registers (2 x 16 packed f16 pairs = 32 VGPR)
                unsigned qreg[2][16];
                #pragma unroll
                for (int r = 0; r < 2; ++r) {
                    if (r < nr) {
                        const u32x4* qp = (const u32x4*)&qs16[hh][(r0 + r) * 56];
                        #pragma unroll
                        for (int w = 0; w < 4; ++w) {
                            u32x4 qv = qp[w];
                            qreg[r][w * 4 + 0] = qv[0];
                            qreg[r][w * 4 + 1] = qv[1];
                            qreg[r][w * 4 + 2] = qv[2];
                            qreg[r][w * 4 + 3] = qv[3];
                        }
                    }
                }

                // logits: lane j8 handles m = j8 + 8i
                float P[2][7];
                #pragma unroll
                for (int i = 0; i < 7; ++i) {
                    int m = j8 + 8 * i;
                    bool vm = m < NT;
                    u32x4 kw0{}, kw1{}, kw2{}, kw3{};
                    if (vm) {
                        const u32x4* kp = (const u32x4*)&ks16[hh][m * 56];
                        kw0 = kp[0]; kw1 = kp[1]; kw2 = kp[2]; kw3 = kp[3];
                    }
                    #pragma unroll
                    for (int r = 0; r < 2; ++r) {
                        float lv = -1e30f;
                        if (r < nr && vm) {
                            float dsum = 0.f;
                            #pragma unroll
                            for (int c = 0; c < 4; ++c) dsum = fdot2u(qreg[r][c], kw0[c], dsum);
                            #pragma unroll
                            for (int c = 0; c < 4; ++c) dsum = fdot2u(qreg[r][4 + c], kw1[c], dsum);
                            #pragma unroll
                            for (int c = 0; c < 4; ++c) dsum = fdot2u(qreg[r][8 + c], kw2[c], dsum);
                            #pragma unroll
                            for (int c = 0; c < 4; ++c) dsum = fdot2u(qreg[r][12 + c], kw3[c], dsum);
                            int idx = (r0 + r) * NT + m;
                            lv = dsum + bT[idx] + mrow[idx];
                        }
                        P[r][i] = lv;
                    }
                }

                // softmax: width-8 butterfly (group-uniform branches)
                #pragma unroll
                for (int r = 0; r < 2; ++r) {
                    if (r < nr) {
                        float mx = P[r][0];
                        #pragma unroll
                        for (int i = 1; i < 7; ++i) mx = fmaxf(mx, P[r][i]);
                        mx = fmaxf(mx, __shfl_xor(mx, 1, 8));
                        mx = fmaxf(mx, __shfl_xor(mx, 2, 8));
                        mx = fmaxf(mx, __shfl_xor(mx, 4, 8));
                        float sm = 0.f;
                        #pragma unroll
                        for (int i = 0; i < 7; ++i) {
                            float e = __expf(P[r][i] - mx);
                            P[r][i] = e; sm += e;
                        }
                        sm += __shfl_xor(sm, 1, 8);
                        sm += __shfl_xor(sm, 2, 8);
                        sm += __shfl_xor(sm, 4, 8);
                        float inv = 1.f / sm;
                        #pragma unroll
                        for (int i = 0; i < 7; ++i) P[r][i] *= inv;
                    }
                }

                // PV: lane owns d = j8*4..+3; P broadcast by width-8 shfl
                f32x4 oacc[2];
                #pragma unroll
                for (int r = 0; r < 2; ++r) oacc[r] = f32x4{0.f, 0.f, 0.f, 0.f};
                #pragma unroll
                for (int i8 = 0; i8 < 7; ++i8) {
                    #pragma unroll
                    for (int jj = 0; jj < 8; ++jj) {
                        const int mm = i8 * 8 + jj;
                        if (mm < NT) {
                            f32x4 v4 = *(const f32x4*)&vs[hh][mm * 36 + j8 * 4];
                            #pragma unroll
                            for (int r = 0; r < 2; ++r) {
                                if (r < nr) {
                                    float p = __shfl(P[r][i8], jj, 8);
                                    oacc[r] += v4 * p;
                                }
                            }
                        }
                    }
                }
                #pragma unroll
                for (int r = 0; r < 2; ++r) {
                    if (r < nr) {
                        *(f32x4*)&y[((size_t)b * NT + (r0 + r)) * DIM + hg * HD + j8 * 4] = oacc[r];
                    }
                }
            }
        }
        // next pass's first __syncthreads() protects LDS
    }
}

// ---- in-place output projection via split-MFMA ----
__global__ __launch_bounds__(256)
void proj_mfma(const u32x4* __restrict__ pwf,
               const float* __restrict__ proj_b,
               float* __restrict__ y)
{
    const int t = threadIdx.x;
    const int lane = t & 63;
    const int wid = t >> 6;
    const int mhalf = wid >> 1, nhalf = wid & 1;
    const int lrow = lane & 15;
    const int lk8 = (lane >> 4) << 3;
    const int lr4 = (lane >> 4) << 2;
    float* yb = y + (size_t)blockIdx.x * (64 * DIM);
    const u32x4* pwl = pwf + lane;

    f32x4 acc[2][12];
    #pragma unroll
    for (int mt = 0; mt < 2; ++mt)
        #pragma unroll
        for (int ln = 0; ln < 12; ++ln)
            acc[mt][ln] = f32x4{0.f, 0.f, 0.f, 0.f};

    for (int kt = 0; kt < 12; ++kt) {
        u32x4 ah[2], al[2];
        #pragma unroll
        for (int mt = 0; mt < 2; ++mt) {
            int row = mhalf * 32 + mt * 16 + lrow;
            const float4* px = (const float4*)(yb + row * DIM + kt * 32 + lk8);
            float4 a = px[0], c = px[1];
            cvt8(a, c, ah[mt], al[mt]);
        }
        #pragma unroll
        for (int ln = 0; ln < 12; ++ln) {
            const u32x4* bp = pwl + (kt * 24 + nhalf * 12 + ln) * 128;
            u32x4 bh = bp[0], bl = bp[64];
            #pragma unroll
            for (int mt = 0; mt < 2; ++mt) {
                acc[mt][ln] = MFMA16(al[mt], bh, acc[mt][ln]);
                acc[mt][ln] = MFMA16(ah[mt], bl, acc[mt][ln]);
                acc[mt][ln] = MFMA16(ah[mt], bh, acc[mt][ln]);
            }
        }
    }
    __syncthreads();   // partner waves still read these rows until here
    #pragma unroll
    for (int ln = 0; ln < 12; ++ln) {
        int col = (nhalf * 12 + ln) * 16 + lrow;
        float bias = proj_b[col];
        #pragma unroll
        for (int mt = 0; mt < 2; ++mt)
            #pragma unroll
            for (int r = 0; r < 4; ++r) {
                int row = mhalf * 32 + mt * 16 + lr4 + r;
                yb[row * DIM + col] = acc[mt][ln][r] + bias;
            }
    }
}

// ================== fallback path (fp32, no-ws) ==================
#define HD_P 33
#define CHUNK 128
#define THREADS_A 384

__global__ __launch_bounds__(THREADS_A)
void win_attn_kernel(const float* __restrict__ x,
                     const float* __restrict__ mask,
                     const float* __restrict__ qkv_w,
                     const float* __restrict__ qkv_b,
                     const float* __restrict__ rpb,
                     const int*   __restrict__ rel,
                     float* __restrict__ y)
{
    __shared__ float xs[NT * CHUNK];
    __shared__ float qs[NT * HD_P];
    __shared__ float ks_[NT * HD_P];
    __shared__ float vsf[NT * HD_P];
    __shared__ float lg[NT * NT];

    const int b = blockIdx.x;
    const int t = threadIdx.x;
    const float* xb = x + (size_t)b * (NT * DIM);
    const float* mrow = mask + (size_t)(b & (NW_MASK - 1)) * (NT * NT);

    const int tx = t % 96;
    const int ty = t / 96;
    const int p  = tx / 32;
    const int d  = tx % 32;

    for (int h = 0; h < NH; ++h) {
        float acc[13];
        #pragma unroll
        for (int i = 0; i < 13; ++i) acc[i] = 0.f;
        const int wcol = p * DIM + h * HD + d;

        for (int c = 0; c < 3; ++c) {
            __syncthreads();
            for (int i = t; i < NT * (CHUNK / 4); i += THREADS_A) {
                int r = i >> 5;
                int j = i & 31;
                ((float4*)xs)[i] = ((const float4*)xb)[r * 96 + c * 32 + j];
            }
            __syncthreads();
            const float4* xs4 = (const float4*)xs;
            const float* wb = qkv_w + (size_t)(c * CHUNK) * (3 * DIM) + wcol;
            for (int kk4 = 0; kk4 < CHUNK / 4; ++kk4) {
                float w0 = wb[(size_t)(kk4 * 4 + 0) * (3 * DIM)];
                float w1 = wb[(size_t)(kk4 * 4 + 1) * (3 * DIM)];
                float w2 = wb[(size_t)(kk4 * 4 + 2) * (3 * DIM)];
                float w3 = wb[(size_t)(kk4 * 4 + 3) * (3 * DIM)];
                #pragma unroll
                for (int i = 0; i < 13; ++i) {
                    int r = ty + 4 * i;
                    if (r < NT) {
                        float4 xv = xs4[r * 32 + kk4];
                        acc[i] += xv.x * w0;
                        acc[i] += xv.y * w1;
                        acc[i] += xv.z * w2;
                        acc[i] += xv.w * w3;
                    }
                }
            }
        }
        float bv = qkv_b[wcol];
        float* dst = (p == 0) ? qs : (p == 1) ? ks_ : vsf;
        #pragma unroll
        for (int i = 0; i < 13; ++i) {
            int r = ty + 4 * i;
            if (r < NT) dst[r * HD_P + d] = acc[i] + bv;
        }
        __syncthreads();

        for (int idx = t; idx < NT * NT; idx += THREADS_A) {
            int n = idx / NT, m = idx % NT;
            float s = 0.f;
            #pragma unroll
            for (int kk = 0; kk < HD; ++kk)
                s += qs[n * HD_P + kk] * ks_[m * HD_P + kk];
            s = s * SCALEF + rpb[rel[idx] * NH + h] + mrow[idx];
            lg[idx] = s;
        }
        __syncthreads();

        if (t < NT) {
            float mx = -1e30f;
            for (int m = 0; m < NT; ++m) mx = fmaxf(mx, lg[t * NT + m]);
            float sum = 0.f;
            for (int m = 0; m < NT; ++m) {
                float e = __expf(lg[t * NT + m] - mx);
                lg[t * NT + m] = e;
                sum += e;
            }
            float inv = 1.f / sum;
            for (int m = 0; m < NT; ++m) lg[t * NT + m] *= inv;
        }
        __syncthreads();

        for (int idx = t; idx < NT * HD; idx += THREADS_A) {
            int n = idx >> 5, dd = idx & 31;
            float s = 0.f;
            #pragma unroll
            for (int m = 0; m < NT; ++m)
                s += lg[n * NT + m] * vsf[m * HD_P + dd];
            y[(size_t)b * (NT * DIM) + n * DIM + h * HD + dd] = s;
        }
    }
}

#define RPB 16
__global__ __launch_bounds__(384)
void proj_kernel(const float* __restrict__ proj_w,
                 const float* __restrict__ proj_b,
                 float* __restrict__ y)
{
    __shared__ float ys[RPB * DIM];
    const int t = threadIdx.x;
    float* base = y + (size_t)blockIdx.x * (RPB * DIM);
    for (int i = t; i < RPB * DIM / 4; i += 384)
        ((float4*)ys)[i] = ((const float4*)base)[i];
    __syncthreads();

    float acc[RPB];
    #pragma unroll
    for (int i = 0; i < RPB; ++i) acc[i] = 0.f;
    const float* wp = proj_w + t;
    const float4* ys4 = (const float4*)ys;
    for (int kk4 = 0; kk4 < DIM / 4; ++kk4) {
        float w0 = wp[(kk4 * 4 + 0) * DIM];
        float w1 = wp[(kk4 * 4 + 1) * DIM];
        float w2 = wp[(kk4 * 4 + 2) * DIM];
        float w3 = wp[(kk4 * 4 + 3) * DIM];
        #pragma unroll
        for (int i = 0; i < RPB; ++i) {
            float4 xv = ys4[i * 96 + kk4];
            acc[i] += xv.x * w0 + xv.y * w1 + xv.z * w2 + xv.w * w3;
        }
    }
    float bv = proj_b[t];
    #pragma unroll
    for (int i = 0; i < RPB; ++i)
        base[i * DIM + t] = acc[i] + bv;
}

// ================== launch ==================
extern "C" void kernel_launch(void* const* d_in, const int* in_sizes, int n_in,
                              void* d_out, int out_size, void* d_ws, size_t ws_size,
                              hipStream_t stream) {
    const float* x      = (const float*)d_in[0];
    const float* mask   = (const float*)d_in[1];
    const float* qkv_w  = (const float*)d_in[2];
    const float* qkv_b  = (const float*)d_in[3];
    const float* proj_w = (const float*)d_in[4];
    const float* proj_b = (const float*)d_in[5];
    const float* rpb    = (const float*)d_in[6];
    const int*   rel    = (const int*)d_in[7];
    float* out = (float*)d_out;

    const size_t WS_FRAG = (size_t)(12 * 96 * 128) * 16;       // 2,359,296 B
    const size_t WS_NEED = WS_FRAG + (size_t)NH * NT * NT * 4; // + 115,248 B
    if (d_ws != nullptr && ws_size >= WS_NEED) {
        u32x4* wf = (u32x4*)d_ws;
        float* biasT = (float*)((char*)d_ws + WS_FRAG);
        conv_w<<<401, 256, 0, stream>>>(qkv_w, proj_w, rpb, rel, wf, biasT);
        attn_mfma<<<NWIN, 256, 0, stream>>>(x, mask, qkv_b, biasT, wf, out);
        proj_mfma<<<(NWIN * NT) / 64, 256, 0, stream>>>(wf + (size_t)(12 * 72 * 128), proj_b, out);
    } else {
        win_attn_kernel<<<NWIN, THREADS_A, 0, stream>>>(x, mask, qkv_w, qkv_b, rpb, rel, out);
        proj_kernel<<<(NWIN * NT) / RPB, 384, 0, stream>>>(proj_w, proj_b, out);
    }
}